// Round 13
// baseline (31.600 us; speedup 1.0000x reference)
//
#include <hip/hip_runtime.h>

typedef __attribute__((ext_vector_type(8))) short bf16x8;
typedef __attribute__((ext_vector_type(4))) float f32x4;

__device__ __forceinline__ unsigned short f2bf(float f){
  union { float f; unsigned int u; } v; v.f = f;
  unsigned int u = v.u;
  return (unsigned short)((u + 0x7FFFu + ((u >> 16) & 1u)) >> 16);  // RNE
}

__device__ __forceinline__ float fast_tanh(float x){
  x = fminf(15.f, fmaxf(-15.f, x));
  float e = __expf(2.f * x);
  return (e - 1.f) / (e + 1.f);
}

__device__ __forceinline__ float dot128(const float* __restrict__ a,
                                        const float* __restrict__ b){
  float s = 0.f;
  for (int c = 0; c < 128; c += 4){
    float4 x = *(const float4*)(a + c);
    float4 y = *(const float4*)(b + c);
    s += x.x*y.x + x.y*y.y + x.z*y.z + x.w*y.w;
  }
  return s;
}

#define GRPSUM(x) { x += __shfl_xor(x, 1); x += __shfl_xor(x, 2); \
                    x += __shfl_xor(x, 4); x += __shfl_xor(x, 8); }

// ws float layout:
//   f[0 .. 6144)    : Bpack  — MFMA1 B-frags (12288 bf16), layer-1 weights
//   f[6144 .. 6912) : B2pack — MFMA2' B-frags (1536 bf16): 3 tiles
//   f[6912 .. 6944) : u'[h]   f[6944..6976): wv[h]
//   f[6976] = rs*(bk2.bq2)    f[6977] = bv2.Wval[0:128]

// ---------------------------------------------------------------------------
// k0: precompute tables (validated r3/r4 version, unchanged)
// ---------------------------------------------------------------------------
__global__ __launch_bounds__(64) void k0_kernel(
    const float* __restrict__ Wk1, const float* __restrict__ Wq1, const float* __restrict__ Wv1,
    const float* __restrict__ Wk2, const float* __restrict__ bk2,
    const float* __restrict__ Wq2, const float* __restrict__ bq2,
    const float* __restrict__ Wv2, const float* __restrict__ bv2,
    const float* __restrict__ Wval, float* __restrict__ ws)
{
  const int tid = blockIdx.x * 64 + threadIdx.x;  // 0..4095
  const float rs = 0.08838834764831845f;          // 1/sqrt(128)
  unsigned short* bp = (unsigned short*)ws;
  unsigned short* b2 = (unsigned short*)(ws + 6144);

  if (tid < 1536){
    const int e = tid & 7, l = (tid >> 3) & 63, tt = tid >> 9;
    const int g = (l >> 4) * 8 + e;
    float val = 0.f;
    if (tt < 2){
      const int h = (l & 15) + tt * 16;
      val = rs * dot128(Wk2 + h * 128, Wq2 + g * 128);
    } else if ((l & 15) == 0){
      val = rs * dot128(Wq2 + g * 128, bk2);
    }
    b2[tid] = f2bf(val);
  } else if (tid < 1600){
    const int h = tid - 1536;
    if (h < 32) ws[6912 + h] = rs * dot128(Wk2 + h * 128, bq2);
    else        ws[6944 + (h - 32)] = dot128(Wv2 + (h - 32) * 128, Wval);
  } else if (tid == 1600){
    ws[6976] = rs * dot128(bk2, bq2);
  } else if (tid == 1601){
    ws[6977] = dot128(bv2, Wval);
  }

  for (int idx = tid; idx < 12288; idx += 4096){
    const int e  = idx & 7;
    const int l  = (idx >> 3) & 63;
    const int kc = (idx >> 9) & 3;
    const int nt = (idx >> 11) & 1;
    const int m  = idx >> 12;
    const float* W1 = (m == 0) ? Wk1 : ((m == 1) ? Wq1 : Wv1);
    const int krow = kc * 32 + (l >> 4) * 8 + e;
    const int col  = nt * 16 + (l & 15);
    bp[idx] = f2bf(W1[krow * 32 + col]);
  }
}

// ---------------------------------------------------------------------------
// fused: ONE block = ONE batch (2048 blocks). Attention split across waves:
//   all waves : noise loads + obs->LDS staging + nv
//   wave 0/1/2: MFMA1 for k/q/v respectively (8 MFMAs each)
//   wave 3    : pv/av
//   wave 0    : score path (MFMA2'/3, softmax, alpha, ov)
//   all       : final combine -> out_x
// No launch_bounds occupancy cap; LDS ~13KB; aims at ~6 blocks/CU resident.
// ---------------------------------------------------------------------------
__global__ __launch_bounds__(256) void fused_kernel(
    const float* __restrict__ obs,
    const float* __restrict__ policies, const float* __restrict__ actions,
    const float* __restrict__ noise, const float* __restrict__ weights,
    const float* __restrict__ bk1p, const float* __restrict__ bq1p, const float* __restrict__ bv1p,
    const float* __restrict__ Wval, const float* __restrict__ bval,
    const float* __restrict__ ws,
    float* __restrict__ out_x, float* __restrict__ out_alpha)
{
  __shared__ __align__(16) float obs_s[16 * 132];        // padded rows (33 f4)
  __shared__ __align__(16) unsigned short hk_s[512];
  __shared__ __align__(16) unsigned short hq_s[512];
  __shared__ __align__(16) unsigned short tq_s[512];
  __shared__ __align__(16) float nvw[256];
  __shared__ __align__(16) float pvl[16], avl[16], vvl[16], rql[16], ovl[16];

  const int t = threadIdx.x;
  const int wid = t >> 6, l = t & 63;
  const int b = blockIdx.x;
  const int li = l & 15, gp = l >> 4;
  const int q8 = l & 7, r8 = l >> 3;

  // ---- A) issue noise loads: 8 x float4 per lane (one latency exposure)
  const float* nbl = noise + (size_t)b * 8192 + (wid * 64 + r8) * 32 + q8 * 4;
  float4 nz[8];
#pragma unroll
  for (int p = 0; p < 8; p++) nz[p] = *(const float4*)(nbl + p * 256);

  // ---- B) issue cooperative obs loads (512 float4 over 256 threads)
  const float4* osrc = (const float4*)(obs + (size_t)b * 2048);
  float4 o0 = osrc[t];
  float4 o1 = osrc[t + 256];
  const float4 wv4 = *(const float4*)(Wval + 128 + q8 * 4);
  const float wscal = weights[0];
  const float bvs = bval[0];

  // ---- C) wave3: pol/act loads
  float4 pA0, pA1, aA0, aA1, wpa, wpb;
  const int jp = l >> 2, seg = l & 3;
  if (wid == 3){
    const float* pp = policies + (size_t)(b * 16 + jp) * 32 + seg * 8;
    const float* ap = actions  + (size_t)(b * 16 + jp) * 32 + seg * 8;
    pA0 = *(const float4*)(pp);
    pA1 = *(const float4*)(pp + 4);
    aA0 = *(const float4*)(ap);
    aA1 = *(const float4*)(ap + 4);
    wpa = *(const float4*)(Wval + 128 + seg * 8);
    wpb = *(const float4*)(Wval + 132 + seg * 8);
  }

  // ---- D) stage obs -> LDS (padded: 33 float4 per 32-f4 row)
  ((float4*)obs_s)[(t >> 5) * 33 + (t & 31)] = o0;
  ((float4*)obs_s)[((t + 256) >> 5) * 33 + ((t + 256) & 31)] = o1;

  // ---- E) consume noise -> nvw
#pragma unroll
  for (int p = 0; p < 8; p++){
    float s = nz[p].x*wv4.x + nz[p].y*wv4.y + nz[p].z*wv4.z + nz[p].w*wv4.w;
    s += __shfl_xor(s, 1); s += __shfl_xor(s, 2); s += __shfl_xor(s, 4);
    if (q8 == 0) nvw[wid * 64 + p * 8 + r8] = s;
  }

  // ---- F) wave3: pv/av
  if (wid == 3){
    float pvv = pA0.x*wpa.x + pA0.y*wpa.y + pA0.z*wpa.z + pA0.w*wpa.w
              + pA1.x*wpb.x + pA1.y*wpb.y + pA1.z*wpb.z + pA1.w*wpb.w;
    float avv = aA0.x*wpa.x + aA0.y*wpa.y + aA0.z*wpa.z + aA0.w*wpa.w
              + aA1.x*wpb.x + aA1.y*wpb.y + aA1.z*wpb.z + aA1.w*wpb.w;
    pvv += __shfl_xor(pvv, 1); pvv += __shfl_xor(pvv, 2);
    avv += __shfl_xor(avv, 1); avv += __shfl_xor(avv, 2);
    if (seg == 0){ pvl[jp] = pvv; avl[jp] = avv; }
  }

  __syncthreads();   // obs_s ready (also nvw/pvl/avl, consumed later)

  // ---- G) waves 0-2: MFMA1 for matrix m = wid (k/q/v)
  if (wid < 3){
    const bf16x8* bp = (const bf16x8*)ws;
    bf16x8 bfr[8];
#pragma unroll
    for (int nt = 0; nt < 2; nt++)
#pragma unroll
      for (int kc = 0; kc < 4; kc++)
        bfr[nt*4+kc] = bp[((wid*2+nt)*4+kc)*64 + l];

    bf16x8 afr[4];
#pragma unroll
    for (int kc = 0; kc < 4; kc++){
      float4 x0 = ((const float4*)obs_s)[li*33 + kc*8 + gp*2];
      float4 x1 = ((const float4*)obs_s)[li*33 + kc*8 + gp*2 + 1];
      bf16x8 a;
      a[0]=(short)f2bf(x0.x); a[1]=(short)f2bf(x0.y);
      a[2]=(short)f2bf(x0.z); a[3]=(short)f2bf(x0.w);
      a[4]=(short)f2bf(x1.x); a[5]=(short)f2bf(x1.y);
      a[6]=(short)f2bf(x1.z); a[7]=(short)f2bf(x1.w);
      afr[kc] = a;
    }
    f32x4 acc0 = {0.f,0.f,0.f,0.f}, acc1 = {0.f,0.f,0.f,0.f};
#pragma unroll
    for (int kc = 0; kc < 4; kc++)
      acc0 = __builtin_amdgcn_mfma_f32_16x16x32_bf16(afr[kc], bfr[kc], acc0, 0, 0, 0);
#pragma unroll
    for (int kc = 0; kc < 4; kc++)
      acc1 = __builtin_amdgcn_mfma_f32_16x16x32_bf16(afr[kc], bfr[4+kc], acc1, 0, 0, 0);

    if (wid == 0){
      const float b0 = bk1p[li], b1 = bk1p[16 + li];
#pragma unroll
      for (int r = 0; r < 4; r++){
        hk_s[(gp*4+r)*32 + li]      = f2bf(fast_tanh(acc0[r] + b0));
        hk_s[(gp*4+r)*32 + 16 + li] = f2bf(fast_tanh(acc1[r] + b1));
      }
    } else if (wid == 1){
      const float b0 = bq1p[li], b1 = bq1p[16 + li];
#pragma unroll
      for (int r = 0; r < 4; r++){
        hq_s[(gp*4+r)*32 + li]      = f2bf(fast_tanh(acc0[r] + b0));
        hq_s[(gp*4+r)*32 + 16 + li] = f2bf(fast_tanh(acc1[r] + b1));
      }
    } else {
      const float b0 = bv1p[li], b1 = bv1p[16 + li];
      const float wv0 = ws[6944 + li], wv1 = ws[6960 + li];
      const float cvv = ws[6977];
      float vp0 = wv0*fast_tanh(acc0[0]+b0) + wv1*fast_tanh(acc1[0]+b1);
      float vp1 = wv0*fast_tanh(acc0[1]+b0) + wv1*fast_tanh(acc1[1]+b1);
      float vp2 = wv0*fast_tanh(acc0[2]+b0) + wv1*fast_tanh(acc1[2]+b1);
      float vp3 = wv0*fast_tanh(acc0[3]+b0) + wv1*fast_tanh(acc1[3]+b1);
      GRPSUM(vp0); GRPSUM(vp1); GRPSUM(vp2); GRPSUM(vp3);
      if (li == 0){
        float4 vq; vq.x = vp0+cvv; vq.y = vp1+cvv; vq.z = vp2+cvv; vq.w = vp3+cvv;
        *(float4*)&vvl[gp*4] = vq;
      }
    }
  }

  __syncthreads();   // hk, hq, vvl ready

  // ---- H) wave0: score path (validated r3 numerics)
  if (wid == 0){
    const bf16x8* b2p = (const bf16x8*)(ws + 6144);
    const bf16x8 b20 = b2p[l], b21 = b2p[64 + l], b22 = b2p[128 + l];
    const float u0 = ws[6912 + li], u1 = ws[6928 + li];
    const float ccv = ws[6976];

    const bf16x8 aq = *(const bf16x8*)(hq_s + li*32 + gp*8);
    f32x4 cu0 = {u0,u0,u0,u0}, cu1 = {u1,u1,u1,u1}, cu2 = {ccv,ccv,ccv,ccv};
    f32x4 tq0 = __builtin_amdgcn_mfma_f32_16x16x32_bf16(aq, b20, cu0, 0, 0, 0);
    f32x4 tq1 = __builtin_amdgcn_mfma_f32_16x16x32_bf16(aq, b21, cu1, 0, 0, 0);
    f32x4 rqt = __builtin_amdgcn_mfma_f32_16x16x32_bf16(aq, b22, cu2, 0, 0, 0);
    if (li == 0){
      float4 rv; rv.x = rqt[0]; rv.y = rqt[1]; rv.z = rqt[2]; rv.w = rqt[3];
      *(float4*)&rql[gp*4] = rv;
    }
#pragma unroll
    for (int r = 0; r < 4; r++){
      tq_s[(gp*4+r)*32 + li]      = f2bf(tq0[r]);
      tq_s[(gp*4+r)*32 + 16 + li] = f2bf(tq1[r]);
    }

    const bf16x8 ak = *(const bf16x8*)(hk_s + li*32 + gp*8);
    const bf16x8 bt = *(const bf16x8*)(tq_s + li*32 + gp*8);
    f32x4 zz = {0.f,0.f,0.f,0.f};
    f32x4 S = __builtin_amdgcn_mfma_f32_16x16x32_bf16(ak, bt, zz, 0, 0, 0);
    const float rc = rql[li];
    float s0 = S[0]+rc, s1 = S[1]+rc, s2 = S[2]+rc, s3 = S[3]+rc;

    // softmax over senders j
    float mx = fmaxf(fmaxf(s0, s1), fmaxf(s2, s3));
    mx = fmaxf(mx, __shfl_xor(mx, 16)); mx = fmaxf(mx, __shfl_xor(mx, 32));
    float e0 = __expf(s0-mx), e1 = __expf(s1-mx), e2 = __expf(s2-mx), e3 = __expf(s3-mx);
    float sm = e0+e1+e2+e3;
    sm += __shfl_xor(sm, 16); sm += __shfl_xor(sm, 32);
    const float inv = 1.f / sm;
    const float a0 = e0*inv, a1 = e1*inv, a2 = e2*inv, a3 = e3*inv;

    // alpha out via LDS transpose (tq_s reused as float[256])
    float* aT = (float*)tq_s;
    { float4 av4x; av4x.x = a0; av4x.y = a1; av4x.z = a2; av4x.w = a3;
      *(float4*)&aT[li*16 + gp*4] = av4x; }
    { float4 o4 = *(const float4*)&aT[l*4];
      *(float4*)(out_alpha + (size_t)b*256 + l*4) = o4; }

    // ov[i] = sum_j alpha[i][j] * vv[j]
    float4 vq4 = *(const float4*)&vvl[gp*4];
    float ovp = a0*vq4.x + a1*vq4.y + a2*vq4.z + a3*vq4.w;
    ovp += __shfl_xor(ovp, 16); ovp += __shfl_xor(ovp, 32);
    if (l < 16) ovl[l] = ovp;
  }

  __syncthreads();   // ovl ready

  // ---- I) combine (all 256 threads): t -> (i = t>>4, j = t&15)  [r9 form]
  {
    const int j = t & 15;
    const float pv = pvl[j], av = avl[j];
    const float zval = wscal * av + (1.f - wscal) * pv + nvw[t];
    float zs = zval;
    GRPSUM(zs);   // sum over the 16 senders j within the i-group
    out_x[(size_t)b * 256 + t] = ovl[j] + (pv - zval + zs) * 0.0625f + bvs;
  }
}

// ---------------------------------------------------------------------------
extern "C" void kernel_launch(void* const* d_in, const int* in_sizes, int n_in,
                              void* d_out, int out_size, void* d_ws, size_t ws_size,
                              hipStream_t stream)
{
  const float* obs      = (const float*)d_in[0];
  const float* policies = (const float*)d_in[1];
  const float* actions  = (const float*)d_in[2];
  const float* weights  = (const float*)d_in[3];
  const float* noise    = (const float*)d_in[4];
  const float* Wk1  = (const float*)d_in[5];
  const float* bk1  = (const float*)d_in[6];
  const float* Wk2  = (const float*)d_in[7];
  const float* bk2  = (const float*)d_in[8];
  const float* Wq1  = (const float*)d_in[9];
  const float* bq1  = (const float*)d_in[10];
  const float* Wq2  = (const float*)d_in[11];
  const float* bq2  = (const float*)d_in[12];
  const float* Wv1  = (const float*)d_in[13];
  const float* bv1  = (const float*)d_in[14];
  const float* Wv2  = (const float*)d_in[15];
  const float* bv2  = (const float*)d_in[16];
  const float* Wval = (const float*)d_in[17];
  const float* bval = (const float*)d_in[18];

  float* out = (float*)d_out;
  float* ws  = (float*)d_ws;

  const int NODES = in_sizes[0] / 128;
  const int B = NODES / 16;

  float* out_x     = out;
  float* out_alpha = out + (size_t)NODES * 16;

  hipLaunchKernelGGL(k0_kernel, dim3(64), dim3(64), 0, stream,
                     Wk1, Wq1, Wv1, Wk2, bk2, Wq2, bq2, Wv2, bv2, Wval, ws);
  hipLaunchKernelGGL(fused_kernel, dim3(B), dim3(256), 0, stream,
                     obs, policies, actions, noise, weights,
                     bk1, bq1, bv1, Wval, bval, ws,
                     out_x, out_alpha);
}